// Round 1
// baseline (33.083 us; speedup 1.0000x reference)
//
#include <hip/hip_runtime.h>
#include <hip/hip_bf16.h>
#include <math.h>

#define NROWS 2048
#define DDIM  32

// ---------------------------------------------------------------------------
// Stage 1: per-column mean and 1/(std+eps) over the batch dim (ddof=1).
// 64 blocks: block b -> array a = b>>5 (0=x,1=y), column d = b&31.
// stats layout (floats): [0..31] mu_x, [32..63] inv_x, [64..95] mu_y, [96..127] inv_y
// ---------------------------------------------------------------------------
__global__ __launch_bounds__(256) void HybridKernel_stats(
    const float* __restrict__ x, const float* __restrict__ y,
    float* __restrict__ stats) {
  __shared__ float ssum[256];
  __shared__ float ssq[256];
  const int b = blockIdx.x;
  const int a = b >> 5;
  const int d = b & 31;
  const float* in = a ? y : x;
  const int t = threadIdx.x;

  float s = 0.f, s2 = 0.f;
  for (int r = t; r < NROWS; r += 256) {
    float v = in[r * DDIM + d];
    s += v;
    s2 = fmaf(v, v, s2);
  }
  ssum[t] = s;
  ssq[t] = s2;
  __syncthreads();
  for (int off = 128; off > 0; off >>= 1) {
    if (t < off) {
      ssum[t] += ssum[t + off];
      ssq[t] += ssq[t + off];
    }
    __syncthreads();
  }
  if (t == 0) {
    const float n = (float)NROWS;
    float mean = ssum[0] / n;
    float var = fmaxf((ssq[0] - ssum[0] * mean) / (n - 1.f), 0.f);
    float inv = 1.f / (sqrtf(var) + 1e-8f);
    stats[a * 64 + d] = mean;
    stats[a * 64 + 32 + d] = inv;
  }
}

// ---------------------------------------------------------------------------
// Stage 2: tiled 64x64 output per 256-thread block; D processed in two
// 16-chunks staged into LDS as float4 (xn, 0.5*cos, 0.5*sin, 0).
// Thread micro-tile 4x4 at (ty+16r, tx+16c).
// classical = exp(2*dot - nx - ny); quantum = prod(0.5 + hcx*cy' + hsx*sy')
// where cy'=cos(y), sy'=sin(y) are carried with the 0.5 folded on the x side
// (0.5+0.5*cos(x-y)); out = 0.5*(classical+quantum).
// ---------------------------------------------------------------------------
#define DT 16

__global__ __launch_bounds__(256, 4) void HybridKernel_main(
    const float* __restrict__ x, const float* __restrict__ y,
    const float* __restrict__ stats, float* __restrict__ out) {
  __shared__ float4 sX4[DT][64];  // (xn, 0.5cos, 0.5sin, 0)
  __shared__ float4 sY4[DT][64];  // (yn,  cos,   sin,  0)  (0.5 folded on x)
  __shared__ float sNX[2][64];
  __shared__ float sNY[2][64];

  const int t = threadIdx.x;
  const int i0 = blockIdx.y * 64;
  const int j0 = blockIdx.x * 64;
  const int tx = t & 15;
  const int ty = t >> 4;

  float acc[4][4];
  float qp[4][4];
#pragma unroll
  for (int r = 0; r < 4; ++r)
#pragma unroll
    for (int c = 0; c < 4; ++c) {
      acc[r][c] = 0.f;
      qp[r][c] = 1.f;
    }

  const int srow = t >> 2;  // 0..63
  const int sq = t & 3;     // 0..3

#pragma unroll
  for (int chunk = 0; chunk < 2; ++chunk) {
    if (chunk) __syncthreads();  // protect LDS overwrite after prior compute
    // ---- stage both sides ----
#pragma unroll
    for (int side = 0; side < 2; ++side) {
      const float* in = side ? y : x;
      const float* mu = stats + side * 64;
      const float* inv = stats + side * 64 + 32;
      float4* sT = side ? &sY4[0][0] : &sX4[0][0];
      float* sNorm = side ? &sNY[chunk][0] : &sNX[chunk][0];
      const int base = side ? j0 : i0;
      const int d0 = chunk * DT + sq * 4;

      const float4 v =
          *reinterpret_cast<const float4*>(&in[(base + srow) * DDIM + d0]);
      float vv[4] = {v.x, v.y, v.z, v.w};
      float nrm = 0.f;
#pragma unroll
      for (int k = 0; k < 4; ++k) {
        const int dg = d0 + k;
        const int dl = sq * 4 + k;
        const float xv = vv[k];
        const float xn = (xv - mu[dg]) * inv[dg];
        nrm = fmaf(xn, xn, nrm);
        float sn, cs;
        __sincosf(xv, &sn, &cs);
        const float scale = side ? 1.0f : 0.5f;  // fold the 0.5 on x side
        sT[dl * 64 + srow] = make_float4(xn, scale * cs, scale * sn, 0.f);
      }
      // reduce nrm across the 4 consecutive lanes sharing this row
      nrm += __shfl_xor(nrm, 1);
      nrm += __shfl_xor(nrm, 2);
      if (sq == 0) sNorm[srow] = nrm;
    }
    __syncthreads();

    // ---- compute ----
#pragma unroll 4
    for (int d = 0; d < DT; ++d) {
      float4 xv4[4];
      float4 yv4[4];
#pragma unroll
      for (int r = 0; r < 4; ++r) xv4[r] = sX4[d][ty + 16 * r];
#pragma unroll
      for (int c = 0; c < 4; ++c) yv4[c] = sY4[d][tx + 16 * c];
#pragma unroll
      for (int r = 0; r < 4; ++r)
#pragma unroll
        for (int c = 0; c < 4; ++c) {
          acc[r][c] = fmaf(xv4[r].x, yv4[c].x, acc[r][c]);
          float term =
              fmaf(xv4[r].y, yv4[c].y, fmaf(xv4[r].z, yv4[c].z, 0.5f));
          qp[r][c] *= term;
        }
    }
  }

  // ---- epilogue ----
  float nx[4], ny[4];
#pragma unroll
  for (int r = 0; r < 4; ++r) nx[r] = sNX[0][ty + 16 * r] + sNX[1][ty + 16 * r];
#pragma unroll
  for (int c = 0; c < 4; ++c) ny[c] = sNY[0][tx + 16 * c] + sNY[1][tx + 16 * c];

#pragma unroll
  for (int r = 0; r < 4; ++r) {
    const int row = i0 + ty + 16 * r;
#pragma unroll
    for (int c = 0; c < 4; ++c) {
      const int col = j0 + tx + 16 * c;
      float cl = __expf(2.f * acc[r][c] - nx[r] - ny[c]);
      out[row * NROWS + col] = 0.5f * (cl + qp[r][c]);
    }
  }
}

extern "C" void kernel_launch(void* const* d_in, const int* in_sizes, int n_in,
                              void* d_out, int out_size, void* d_ws,
                              size_t ws_size, hipStream_t stream) {
  const float* x = (const float*)d_in[0];
  const float* y = (const float*)d_in[1];
  float* stats = (float*)d_ws;  // 128 floats
  float* out = (float*)d_out;

  HybridKernel_stats<<<64, 256, 0, stream>>>(x, y, stats);
  dim3 grid(NROWS / 64, NROWS / 64);
  HybridKernel_main<<<grid, 256, 0, stream>>>(x, y, stats, out);
}

// Round 2
// 32.988 us; speedup vs baseline: 1.0029x; 1.0029x over previous
//
#include <hip/hip_runtime.h>
#include <math.h>

#define NROWS 2048
#define DDIM 32
#define SBLK 16               // stats blocks per array
#define SROWS (NROWS / SBLK)  // 128 rows per stats block

// ---------------------------------------------------------------------------
// Stage 1: coalesced per-column partial sums. 32 blocks; block b covers
// array a=b>>4, rows [blk*128, blk*128+128). part[b][0:32]=sum, [32:64]=sumsq.
// ---------------------------------------------------------------------------
__global__ __launch_bounds__(256) void HybridKernel_stats_partial(
    const float* __restrict__ x, const float* __restrict__ y,
    float* __restrict__ part) {
  const int b = blockIdx.x;
  const int a = b >> 4;
  const int blk = b & (SBLK - 1);
  const float* in = a ? y : x;
  const int t = threadIdx.x;
  const int col = t & 31;
  const int rg = t >> 5;  // 0..7
  float s = 0.f, s2 = 0.f;
  const int r0 = blk * SROWS + rg;
#pragma unroll
  for (int i = 0; i < SROWS / 8; ++i) {
    float v = in[(r0 + i * 8) * DDIM + col];
    s += v;
    s2 = fmaf(v, v, s2);
  }
  __shared__ float ss[8][32];
  __shared__ float sq[8][32];
  ss[rg][col] = s;
  sq[rg][col] = s2;
  __syncthreads();
  if (t < 32) {
    float S = 0.f, Q = 0.f;
#pragma unroll
    for (int g = 0; g < 8; ++g) {
      S += ss[g][t];
      Q += sq[g][t];
    }
    part[b * 64 + t] = S;
    part[b * 64 + 32 + t] = Q;
  }
}

// ---------------------------------------------------------------------------
// Stage 2: 128x128 tile per 256-thread block (8x8 per thread), full D=32
// staged once. LDS layout (per side):
//   sXn[(q*128+row)^q]        float4 = xn[d=4q..4q+3]          (16 KB)
//   sCS[(dp*128+row)^(dp&7)]  float4 = (hc,hs) for d=2dp,2dp+1 (32 KB)
// x side folds the 0.5: hc=0.5cos, hs=0.5sin; y side plain cos/sin.
// term = 0.5 + hcx*cy + hsx*sy ; classical = exp(2*dot - nx - ny).
// ---------------------------------------------------------------------------
__device__ __forceinline__ float f4get(const float4& v, int i) {
  switch (i) {
    case 0: return v.x;
    case 1: return v.y;
    case 2: return v.z;
    default: return v.w;
  }
}

__global__ __launch_bounds__(256, 1) void HybridKernel_main(
    const float* __restrict__ x, const float* __restrict__ y,
    const float* __restrict__ part, float* __restrict__ out) {
  __shared__ float4 sXn[2][1024];
  __shared__ float4 sCS[2][2048];
  __shared__ float sNrm[2][128];
  __shared__ float sMu[2][32];
  __shared__ float sInv[2][32];

  const int t = threadIdx.x;
  const int i0 = blockIdx.y * 128;
  const int j0 = blockIdx.x * 128;

  // --- finalize stats (mean, 1/(std+eps), ddof=1) ---
  if (t < 64) {
    const int a = t >> 5;
    const int c = t & 31;
    float S = 0.f, Q = 0.f;
#pragma unroll
    for (int bb = 0; bb < SBLK; ++bb) {
      S += part[(a * SBLK + bb) * 64 + c];
      Q += part[(a * SBLK + bb) * 64 + 32 + c];
    }
    const float n = (float)NROWS;
    const float mean = S / n;
    const float var = fmaxf((Q - S * mean) / (n - 1.f), 0.f);
    sMu[a][c] = mean;
    sInv[a][c] = 1.f / (sqrtf(var) + 1e-8f);
  }
  __syncthreads();

  // --- staging: per side 128 rows x 8 quads; thread -> (row=u>>3, q=u&7) ---
#pragma unroll
  for (int side = 0; side < 2; ++side) {
    const float* in = side ? y : x;
    const int base = side ? j0 : i0;
    const float sc = side ? 1.0f : 0.5f;
#pragma unroll
    for (int rep = 0; rep < 4; ++rep) {
      const int u = t + 256 * rep;
      const int row = u >> 3;
      const int q = u & 7;
      const float4 g =
          *reinterpret_cast<const float4*>(&in[(base + row) * DDIM + q * 4]);
      const float gv[4] = {g.x, g.y, g.z, g.w};
      float xn[4], hc[4], hs[4];
      float nrm = 0.f;
#pragma unroll
      for (int k = 0; k < 4; ++k) {
        const int d = q * 4 + k;
        xn[k] = (gv[k] - sMu[side][d]) * sInv[side][d];
        nrm = fmaf(xn[k], xn[k], nrm);
        float sn, cs;
        __sincosf(gv[k], &sn, &cs);
        hc[k] = sc * cs;
        hs[k] = sc * sn;
      }
      sXn[side][(q * 128 + row) ^ q] = make_float4(xn[0], xn[1], xn[2], xn[3]);
      const int dp0 = 2 * q, dp1 = 2 * q + 1;
      sCS[side][(dp0 * 128 + row) ^ (dp0 & 7)] =
          make_float4(hc[0], hs[0], hc[1], hs[1]);
      sCS[side][(dp1 * 128 + row) ^ (dp1 & 7)] =
          make_float4(hc[2], hs[2], hc[3], hs[3]);
      nrm += __shfl_xor(nrm, 1);
      nrm += __shfl_xor(nrm, 2);
      nrm += __shfl_xor(nrm, 4);
      if ((t & 7) == 0) sNrm[side][row] = nrm;
    }
  }
  __syncthreads();

  // --- main compute: 8x8 outputs per thread ---
  const int tx = t & 15;
  const int ty = t >> 4;

  float acc[8][8];
  float qp[8][8];
#pragma unroll
  for (int r = 0; r < 8; ++r)
#pragma unroll
    for (int c = 0; c < 8; ++c) {
      acc[r][c] = 0.f;
      qp[r][c] = 1.f;
    }

#pragma unroll 1
  for (int q = 0; q < 8; ++q) {
    float4 xnx[8], xny[8];
#pragma unroll
    for (int r = 0; r < 8; ++r)
      xnx[r] = sXn[0][(q * 128 + ty + 16 * r) ^ q];
#pragma unroll
    for (int c = 0; c < 8; ++c)
      xny[c] = sXn[1][(q * 128 + tx + 16 * c) ^ q];
#pragma unroll
    for (int h = 0; h < 2; ++h) {
      const int dp = 2 * q + h;
      const int sw = dp & 7;
      float4 csx[8], csy[8];
#pragma unroll
      for (int r = 0; r < 8; ++r)
        csx[r] = sCS[0][(dp * 128 + ty + 16 * r) ^ sw];
#pragma unroll
      for (int c = 0; c < 8; ++c)
        csy[c] = sCS[1][(dp * 128 + tx + 16 * c) ^ sw];
#pragma unroll
      for (int dd = 0; dd < 2; ++dd) {
        float xr[8], yr[8], hcx[8], hsx[8], hcy[8], hsy[8];
#pragma unroll
        for (int r = 0; r < 8; ++r) {
          xr[r] = f4get(xnx[r], 2 * h + dd);
          hcx[r] = f4get(csx[r], 2 * dd);
          hsx[r] = f4get(csx[r], 2 * dd + 1);
        }
#pragma unroll
        for (int c = 0; c < 8; ++c) {
          yr[c] = f4get(xny[c], 2 * h + dd);
          hcy[c] = f4get(csy[c], 2 * dd);
          hsy[c] = f4get(csy[c], 2 * dd + 1);
        }
#pragma unroll
        for (int r = 0; r < 8; ++r)
#pragma unroll
          for (int c = 0; c < 8; ++c) {
            acc[r][c] = fmaf(xr[r], yr[c], acc[r][c]);
            const float term =
                fmaf(hcx[r], hcy[c], fmaf(hsx[r], hsy[c], 0.5f));
            qp[r][c] *= term;
          }
      }
    }
  }

  // --- epilogue ---
  float nx[8], ny[8];
#pragma unroll
  for (int r = 0; r < 8; ++r) nx[r] = sNrm[0][ty + 16 * r];
#pragma unroll
  for (int c = 0; c < 8; ++c) ny[c] = sNrm[1][tx + 16 * c];

#pragma unroll
  for (int r = 0; r < 8; ++r) {
    const int row = i0 + ty + 16 * r;
    float* o = out + (size_t)row * NROWS + j0;
#pragma unroll
    for (int c = 0; c < 8; ++c) {
      const float cl = __expf(2.f * acc[r][c] - nx[r] - ny[c]);
      o[tx + 16 * c] = 0.5f * (cl + qp[r][c]);
    }
  }
}

extern "C" void kernel_launch(void* const* d_in, const int* in_sizes, int n_in,
                              void* d_out, int out_size, void* d_ws,
                              size_t ws_size, hipStream_t stream) {
  const float* x = (const float*)d_in[0];
  const float* y = (const float*)d_in[1];
  float* part = (float*)d_ws;  // 2*SBLK*64 = 2048 floats
  float* out = (float*)d_out;

  HybridKernel_stats_partial<<<2 * SBLK, 256, 0, stream>>>(x, y, part);
  dim3 grid(NROWS / 128, NROWS / 128);
  HybridKernel_main<<<grid, 256, 0, stream>>>(x, y, part, out);
}

// Round 3
// 32.863 us; speedup vs baseline: 1.0067x; 1.0038x over previous
//
#include <hip/hip_runtime.h>
#include <math.h>

#define NROWS 2048
#define DDIM 32
#define SBLK 16               // stats blocks per array
#define SROWS (NROWS / SBLK)  // 128 rows per stats block

// ---------------------------------------------------------------------------
// Stage 1: coalesced per-column partial sums. 32 blocks; block b covers
// array a=b>>4, rows [blk*128, blk*128+128). part[b][0:32]=sum, [32:64]=sumsq.
// ---------------------------------------------------------------------------
__global__ __launch_bounds__(256) void HybridKernel_stats_partial(
    const float* __restrict__ x, const float* __restrict__ y,
    float* __restrict__ part) {
  const int b = blockIdx.x;
  const int a = b >> 4;
  const int blk = b & (SBLK - 1);
  const float* in = a ? y : x;
  const int t = threadIdx.x;
  const int col = t & 31;
  const int rg = t >> 5;  // 0..7
  float s = 0.f, s2 = 0.f;
  const int r0 = blk * SROWS + rg;
#pragma unroll
  for (int i = 0; i < SROWS / 8; ++i) {
    float v = in[(r0 + i * 8) * DDIM + col];
    s += v;
    s2 = fmaf(v, v, s2);
  }
  __shared__ float ss[8][32];
  __shared__ float sq[8][32];
  ss[rg][col] = s;
  sq[rg][col] = s2;
  __syncthreads();
  if (t < 32) {
    float S = 0.f, Q = 0.f;
#pragma unroll
    for (int g = 0; g < 8; ++g) {
      S += ss[g][t];
      Q += sq[g][t];
    }
    part[b * 64 + t] = S;
    part[b * 64 + 32 + t] = Q;
  }
}

// ---------------------------------------------------------------------------
// Stage 2: 128x128 tile, 256 threads, 8x8 micro-tile.
// Unified LDS slot array sD[side][s*128 + (row ^ (s&7))], 24 slots per side:
//   s = 0..15 : cos/sin d-pair dp=s -> float4 (hc0,hs0,hc1,hs1), d = 2s,2s+1
//   s = 16..23: xn quad q=s-16     -> float4 xn[4q..4q+3]
// x side folds ALPHA: hc=0.5cos(x), hs=0.5sin(x); y side plain cos/sin.
// Compute runs 24 phases (q-major: C, Q0, Q1), register double-buffered:
// phase p+1's 16 ds_read_b128 are issued before phase p's FMAs.
// classical = exp(2*dot - nx - ny); quantum term = 0.5 + hcx*cy + hsx*sy.
// ---------------------------------------------------------------------------
__global__ __launch_bounds__(256, 1) void HybridKernel_main(
    const float* __restrict__ x, const float* __restrict__ y,
    const float* __restrict__ part, float* __restrict__ out) {
  __shared__ float4 sD[2][24 * 128];
  __shared__ float sNrm[2][128];
  __shared__ float sMu[2][32];
  __shared__ float sInv[2][32];

  const int t = threadIdx.x;
  const int i0 = blockIdx.y * 128;
  const int j0 = blockIdx.x * 128;

  // --- finalize stats (mean, 1/(std+eps), ddof=1) ---
  if (t < 64) {
    const int a = t >> 5;
    const int c = t & 31;
    float S = 0.f, Q = 0.f;
#pragma unroll
    for (int bb = 0; bb < SBLK; ++bb) {
      S += part[(a * SBLK + bb) * 64 + c];
      Q += part[(a * SBLK + bb) * 64 + 32 + c];
    }
    const float n = (float)NROWS;
    const float mean = S / n;
    const float var = fmaxf((Q - S * mean) / (n - 1.f), 0.f);
    sMu[a][c] = mean;
    sInv[a][c] = 1.f / (sqrtf(var) + 1e-8f);
  }
  __syncthreads();

  // --- staging: per side 128 rows x 8 quads; u -> (row=u>>3, q=u&7) ---
#pragma unroll
  for (int side = 0; side < 2; ++side) {
    const float* in = side ? y : x;
    const int base = side ? j0 : i0;
    const float sc = side ? 1.0f : 0.5f;
#pragma unroll
    for (int rep = 0; rep < 4; ++rep) {
      const int u = t + 256 * rep;
      const int row = u >> 3;
      const int q = u & 7;
      const float4 g =
          *reinterpret_cast<const float4*>(&in[(base + row) * DDIM + q * 4]);
      const float gv[4] = {g.x, g.y, g.z, g.w};
      float xn[4], hc[4], hs[4];
      float nrm = 0.f;
#pragma unroll
      for (int k = 0; k < 4; ++k) {
        const int d = q * 4 + k;
        xn[k] = (gv[k] - sMu[side][d]) * sInv[side][d];
        nrm = fmaf(xn[k], xn[k], nrm);
        float sn, cs;
        __sincosf(gv[k], &sn, &cs);
        hc[k] = sc * cs;
        hs[k] = sc * sn;
      }
      sD[side][(16 + q) * 128 + (row ^ q)] =
          make_float4(xn[0], xn[1], xn[2], xn[3]);
      const int dp0 = 2 * q, dp1 = 2 * q + 1;
      sD[side][dp0 * 128 + (row ^ (dp0 & 7))] =
          make_float4(hc[0], hs[0], hc[1], hs[1]);
      sD[side][dp1 * 128 + (row ^ (dp1 & 7))] =
          make_float4(hc[2], hs[2], hc[3], hs[3]);
      nrm += __shfl_xor(nrm, 1);
      nrm += __shfl_xor(nrm, 2);
      nrm += __shfl_xor(nrm, 4);
      if ((t & 7) == 0) sNrm[side][row] = nrm;
    }
  }
  __syncthreads();

  // --- main compute: 24 phases, double-buffered fragments ---
  const int tx = t & 15;
  const int ty = t >> 4;
  const float4* sD0 = &sD[0][0];
  const float4* sD1 = &sD[1][0];

  float acc[8][8];
  float qp[8][8];
#pragma unroll
  for (int r = 0; r < 8; ++r)
#pragma unroll
    for (int c = 0; c < 8; ++c) {
      acc[r][c] = 0.f;
      qp[r][c] = 1.f;
    }

  float4 fxA[8], fyA[8], fxB[8], fyB[8];

  auto loadp = [&](int s, float4* FX, float4* FY) {
    const int sw = s & 7;
    const float4* bx = sD0 + s * 128 + (ty ^ sw);
    const float4* by = sD1 + s * 128 + (tx ^ sw);
#pragma unroll
    for (int i = 0; i < 8; ++i) {
      FX[i] = bx[16 * i];
      FY[i] = by[16 * i];
    }
  };
  auto sfromp = [](int p) {
    const int q = (p * 11) >> 5;  // p/3 for p in [0,31]
    const int k = p - 3 * q;
    return (k == 0) ? (16 + q) : (2 * q + k - 1);
  };
  auto compC = [&](const float4* FX, const float4* FY) {
#pragma unroll
    for (int r = 0; r < 8; ++r)
#pragma unroll
      for (int c = 0; c < 8; ++c) {
        float a = acc[r][c];
        a = fmaf(FX[r].x, FY[c].x, a);
        a = fmaf(FX[r].y, FY[c].y, a);
        a = fmaf(FX[r].z, FY[c].z, a);
        a = fmaf(FX[r].w, FY[c].w, a);
        acc[r][c] = a;
      }
  };
  auto compQ = [&](const float4* FX, const float4* FY) {
#pragma unroll
    for (int r = 0; r < 8; ++r)
#pragma unroll
      for (int c = 0; c < 8; ++c) {
        const float t0 =
            fmaf(FX[r].x, FY[c].x, fmaf(FX[r].y, FY[c].y, 0.5f));
        const float t1 =
            fmaf(FX[r].z, FY[c].z, fmaf(FX[r].w, FY[c].w, 0.5f));
        qp[r][c] *= t0 * t1;
      }
  };

  loadp(16, fxA, fyA);  // phase 0 = (q=0, C)
#pragma unroll 1
  for (int p = 0; p < 24; p += 2) {
    loadp(sfromp(p + 1), fxB, fyB);
    if (p % 3 == 0)
      compC(fxA, fyA);
    else
      compQ(fxA, fyA);
    const int p2 = p + 2;
    loadp(p2 < 24 ? sfromp(p2) : 0, fxA, fyA);
    if ((p + 1) % 3 == 0)
      compC(fxB, fyB);
    else
      compQ(fxB, fyB);
  }

  // --- epilogue ---
  float nx[8], ny[8];
#pragma unroll
  for (int r = 0; r < 8; ++r) nx[r] = sNrm[0][ty + 16 * r];
#pragma unroll
  for (int c = 0; c < 8; ++c) ny[c] = sNrm[1][tx + 16 * c];

#pragma unroll
  for (int r = 0; r < 8; ++r) {
    const int row = i0 + ty + 16 * r;
    float* o = out + (size_t)row * NROWS + j0;
#pragma unroll
    for (int c = 0; c < 8; ++c) {
      const float cl = __expf(2.f * acc[r][c] - nx[r] - ny[c]);
      o[tx + 16 * c] = 0.5f * (cl + qp[r][c]);
    }
  }
}

extern "C" void kernel_launch(void* const* d_in, const int* in_sizes, int n_in,
                              void* d_out, int out_size, void* d_ws,
                              size_t ws_size, hipStream_t stream) {
  const float* x = (const float*)d_in[0];
  const float* y = (const float*)d_in[1];
  float* part = (float*)d_ws;  // 2*SBLK*64 = 2048 floats
  float* out = (float*)d_out;

  HybridKernel_stats_partial<<<2 * SBLK, 256, 0, stream>>>(x, y, part);
  dim3 grid(NROWS / 128, NROWS / 128);
  HybridKernel_main<<<grid, 256, 0, stream>>>(x, y, part, out);
}